// Round 11
// baseline (488.768 us; speedup 1.0000x reference)
//
#include <hip/hip_runtime.h>
#include <hip/hip_bf16.h>
#include <hip/hip_fp16.h>

#define NFEAT 128
#define NHID  256
#define NCLASS 40
#define THRESH 0.1f
#define FEPS   1e-8f
#define GUARD  1e-3f

struct h2x2 { __half2 a, b; };   // 8-byte packed 4x fp16

typedef _Float16 v2h __attribute__((ext_vector_type(2)));

// fdot2: s += dot(2xfp16, 2xfp16) in one VALU op where available
__device__ __forceinline__ float dot2acc(unsigned int a, unsigned int b, float s) {
#if __has_builtin(__builtin_amdgcn_fdot2)
    return __builtin_amdgcn_fdot2(__builtin_bit_cast(v2h, a),
                                  __builtin_bit_cast(v2h, b), s, false);
#else
    float2 fa = __half22float2(__builtin_bit_cast(__half2, a));
    float2 fb = __half22float2(__builtin_bit_cast(__half2, b));
    return s + fa.x * fb.x + fa.y * fb.y;
#endif
}

__device__ __forceinline__ float waveSum(float v) {
#pragma unroll
    for (int off = 32; off > 0; off >>= 1) v += __shfl_xor(v, off, 64);
    return v;
}

__device__ __forceinline__ float halfSum(float v) {
#pragma unroll
    for (int off = 16; off > 0; off >>= 1) v += __shfl_xor(v, off, 64);
    return v;
}

__device__ __forceinline__ float qSum16(float v) {
#pragma unroll
    for (int off = 8; off > 0; off >>= 1) v += __shfl_xor(v, off, 64);
    return v;
}

// ---- prep: nrm + normalized fp16 xn + zero-init deg/counts (wave per node) ----
__global__ void k_prep(const float* __restrict__ x, __half2* __restrict__ xn,
                       float* __restrict__ nrm, float* __restrict__ deg,
                       int* __restrict__ counts, int N) {
    int r = (blockIdx.x * blockDim.x + threadIdx.x) >> 6;
    int lane = threadIdx.x & 63;
    if (r >= N) return;
    float2 a = ((const float2*)(x + (size_t)r * NFEAT))[lane];
    float s = waveSum(a.x * a.x + a.y * a.y);
    float nr = fmaxf(sqrtf(s), FEPS);
    float inv = 1.0f / nr;
    xn[(size_t)r * (NFEAT / 2) + lane] = __floats2half2_rn(a.x * inv, a.y * inv);
    if (lane == 0) {
        nrm[r] = nr;
        deg[r] = 0.0f;
        counts[r] = 0;
    }
}

// ---- att1: 4 edges/wave (16-lane groups) over normalized fp16 x; fdot2 ----
__global__ void k_att1(const float* __restrict__ xf, const __half2* __restrict__ xn,
                       const int* __restrict__ row, const int* __restrict__ col,
                       const float* __restrict__ nrm,
                       float* __restrict__ w1, float* __restrict__ deg,
                       int* __restrict__ counts, int E) {
    int wid = (blockIdx.x * blockDim.x + threadIdx.x) >> 6;
    int lane = threadIdx.x & 63;
    int g = lane >> 4, l16 = lane & 15;
    int e = wid * 4 + g;
    if (e >= E) return;
    int r = row[e], c = col[e];
    uint4 av = ((const uint4*)(xn + (size_t)r * (NFEAT / 2)))[l16];
    uint4 bv = ((const uint4*)(xn + (size_t)c * (NFEAT / 2)))[l16];
    float s = 0.f;
    s = dot2acc(av.x, bv.x, s);
    s = dot2acc(av.y, bv.y, s);
    s = dot2acc(av.z, bv.z, s);
    s = dot2acc(av.w, bv.w, s);
    float sims = qSum16(s);
    if (__builtin_expect(fabsf(sims - THRESH) < GUARD, 0)) {
        const float4* fr = (const float4*)(xf + (size_t)r * NFEAT);
        const float4* fc = (const float4*)(xf + (size_t)c * NFEAT);
        float4 a0 = fr[l16], a1 = fr[l16 + 16];
        float4 b0 = fc[l16], b1 = fc[l16 + 16];
        float s2 = qSum16(a0.x * b0.x + a0.y * b0.y + a0.z * b0.z + a0.w * b0.w +
                          a1.x * b1.x + a1.y * b1.y + a1.z * b1.z + a1.w * b1.w);
        sims = s2 / (nrm[r] * nrm[c]);
    }
    if (l16 == 0) {
        float w = (sims >= THRESH && r != c) ? sims : 0.0f;
        w1[e] = w;
        if (w != 0.0f) {
            unsafeAtomicAdd(&deg[r], w);
            atomicAdd(&counts[r], 1);
        }
    }
}

// ---- exclusive scan of counts -> rowptr (3-kernel, N <= 512*256) ----
__global__ __launch_bounds__(256) void k_scan1(const int* __restrict__ counts,
                                               int* __restrict__ rowptr,
                                               int* __restrict__ bsum, int N) {
    __shared__ int tmp[256];
    int t = threadIdx.x, i = blockIdx.x * 256 + t;
    int v = (i < N) ? counts[i] : 0;
    tmp[t] = v;
    __syncthreads();
    for (int off = 1; off < 256; off <<= 1) {
        int add = (t >= off) ? tmp[t - off] : 0;
        __syncthreads();
        tmp[t] += add;
        __syncthreads();
    }
    if (i < N) rowptr[i] = tmp[t] - v;
    if (t == 255) bsum[blockIdx.x] = tmp[t];
}

__global__ __launch_bounds__(512) void k_scan2(int* __restrict__ bsum, int nb) {
    __shared__ int tmp[512];
    int t = threadIdx.x;
    int v = (t < nb) ? bsum[t] : 0;
    tmp[t] = v;
    __syncthreads();
    for (int off = 1; off < 512; off <<= 1) {
        int add = (t >= off) ? tmp[t - off] : 0;
        __syncthreads();
        tmp[t] += add;
        __syncthreads();
    }
    if (t < nb) bsum[t] = tmp[t] - v;
}

__global__ void k_scan3(int* __restrict__ rowptr, const int* __restrict__ bsum, int N) {
    int i = blockIdx.x * 256 + threadIdx.x;
    if (i < N) rowptr[i] += bsum[blockIdx.x];
}

// ---- fill CSR: edata[pos] = (col, norm); dinv computed inline from deg ----
__global__ void k_fill(const int* __restrict__ row, const int* __restrict__ col,
                       const float* __restrict__ wbuf, const float* __restrict__ deg,
                       int* __restrict__ rowptr, int2* __restrict__ edata, int E) {
    int e = blockIdx.x * blockDim.x + threadIdx.x;
    if (e >= E) return;
    float w = wbuf[e];
    if (w == 0.0f) return;
    int r = row[e], c = col[e];
    float dr = 1.0f / sqrtf(1.0f + deg[r]);
    float dc = 1.0f / sqrtf(1.0f + deg[c]);
    float nm = dr * w * dc;
    int pos = atomicAdd(&rowptr[r], 1);
    edata[pos] = make_int2(c, __float_as_int(nm));
}

// ---- gather1: xagg[r] = dinv^2*x[r] + sum_e nm*x[c]  (wave per node, f32) ----
__global__ void k_gather1(const float* __restrict__ xf, const int* __restrict__ rowptr,
                          const int* __restrict__ counts, const float* __restrict__ deg,
                          const int2* __restrict__ edata, float* __restrict__ xagg, int N) {
    int r = (blockIdx.x * blockDim.x + threadIdx.x) >> 6;
    int lane = threadIdx.x & 63;
    if (r >= N) return;
    int cnt = counts[r];
    int start = rowptr[r] - cnt;
    float d = 1.0f / sqrtf(1.0f + deg[r]);
    float2 xa = ((const float2*)(xf + (size_t)r * NFEAT))[lane];
    float2 acc = make_float2(d * d * xa.x, d * d * xa.y);
    for (int k = 0; k < cnt; ++k) {
        int2 ed = edata[start + k];
        float nm = __int_as_float(ed.y);
        float2 xv = ((const float2*)(xf + (size_t)ed.x * NFEAT))[lane];
        acc.x += nm * xv.x;
        acc.y += nm * xv.y;
    }
    ((float2*)(xagg + (size_t)r * NFEAT))[lane] = acc;
}

// ---- gemm1h v6: 64x256 block tile, 8n x (4+4)j thread tile, split-half cols
//      (stride-16B wsh reads, conflict-free); NO f32 h store — emits fp16 hh + norms ----
__global__ __launch_bounds__(256) void k_gemm1h(const float* __restrict__ xagg,
                                                const float* __restrict__ W1f,
                                                const float* __restrict__ b1f,
                                                __half2* __restrict__ hh,
                                                float* __restrict__ nrm2, int N) {
    __shared__ float xs[64][NFEAT + 4];   // [64][132], 33.8 KB
    __shared__ float wsh[16][NHID];       // 16 KB W1 chunk
    __shared__ float red[8][8];
    int tid = threadIdx.x;
    int i0 = blockIdx.x * 64;

    // stage xs: 2048 float4, coalesced, conflict-free
#pragma unroll
    for (int it = 0; it < 8; ++it) {
        int idx4 = it * 256 + tid;
        int n = idx4 >> 5, kq = idx4 & 31;
        int i = i0 + n;
        float4 v = make_float4(0.f, 0.f, 0.f, 0.f);
        if (i < N) v = ((const float4*)(xagg + (size_t)i * NFEAT))[kq];
        *((float4*)&xs[n][kq * 4]) = v;
    }

    int jg = tid & 31;            // col group: cols jg*4..+3 and 128+jg*4..+3
    int ng = tid >> 5;            // node group: nodes ng*8 .. +7
    int jA = jg * 4;

    float acc[8][8];
#pragma unroll
    for (int a = 0; a < 8; ++a)
#pragma unroll
        for (int b = 0; b < 8; ++b) acc[a][b] = 0.f;

    for (int kc = 0; kc < NFEAT; kc += 16) {
        __syncthreads();
        // stage W1 chunk [16][256]: 1024 float4
#pragma unroll
        for (int it = 0; it < 4; ++it) {
            int idx4 = it * 256 + tid;
            int kr = idx4 >> 6, jq = idx4 & 63;
            float4 v = ((const float4*)(W1f + (size_t)(kc + kr) * NHID))[jq];
            *((float4*)&wsh[kr][jq * 4]) = v;
        }
        __syncthreads();
#pragma unroll
        for (int kr = 0; kr < 16; kr += 4) {
            // 8 nodes x 4 features: b128 broadcasts (2 addrs/wave)
            float4 xv[8];
#pragma unroll
            for (int a = 0; a < 8; ++a)
                xv[a] = *((const float4*)&xs[ng * 8 + a][kc + kr]);
#pragma unroll
            for (int t = 0; t < 4; ++t) {
                float4 wa = *((const float4*)&wsh[kr + t][jA]);        // stride 16B
                float4 wb = *((const float4*)&wsh[kr + t][128 + jA]);  // stride 16B
                float wv[8] = {wa.x, wa.y, wa.z, wa.w, wb.x, wb.y, wb.z, wb.w};
#pragma unroll
                for (int a = 0; a < 8; ++a) {
                    float xt = ((const float*)&xv[a])[t];
#pragma unroll
                    for (int b = 0; b < 8; ++b) acc[a][b] += xt * wv[b];
                }
            }
        }
    }

    float bA[8];
#pragma unroll
    for (int q = 0; q < 4; ++q) { bA[q] = b1f[jA + q]; bA[4 + q] = b1f[128 + jA + q]; }

#pragma unroll
    for (int a = 0; a < 8; ++a) {
        int i = i0 + ng * 8 + a;
        float4 va, vb;
        va.x = fmaxf(acc[a][0] + bA[0], 0.f);
        va.y = fmaxf(acc[a][1] + bA[1], 0.f);
        va.z = fmaxf(acc[a][2] + bA[2], 0.f);
        va.w = fmaxf(acc[a][3] + bA[3], 0.f);
        vb.x = fmaxf(acc[a][4] + bA[4], 0.f);
        vb.y = fmaxf(acc[a][5] + bA[5], 0.f);
        vb.z = fmaxf(acc[a][6] + bA[6], 0.f);
        vb.w = fmaxf(acc[a][7] + bA[7], 0.f);
        if (i < N) {
            __half2* hhrow = hh + (size_t)i * (NHID / 2);
            h2x2 pa = { __floats2half2_rn(va.x, va.y), __floats2half2_rn(va.z, va.w) };
            h2x2 pb = { __floats2half2_rn(vb.x, vb.y), __floats2half2_rn(vb.z, vb.w) };
            *((h2x2*)(hhrow + (jA >> 1))) = pa;
            *((h2x2*)(hhrow + 64 + (jA >> 1))) = pb;
        }
        float p = va.x * va.x + va.y * va.y + va.z * va.z + va.w * va.w +
                  vb.x * vb.x + vb.y * vb.y + vb.z * vb.z + vb.w * vb.w;
        p = halfSum(p);                 // reduce over jg within 32-lane half
        if (jg == 0) red[ng][a] = p;
    }
    __syncthreads();
    if (tid < 64) {
        int i = i0 + tid;
        if (i < N) nrm2[i] = fmaxf(sqrtf(red[tid >> 3][tid & 7]), FEPS);
    }
}

// ---- att2 over CSR from fp16 h (fdot2); guard recomputes h rows from xagg@W1 ----
__global__ void k_att2csr(const float* __restrict__ xagg, const float* __restrict__ W1f,
                          const float* __restrict__ b1f, const __half2* __restrict__ hh,
                          const int* __restrict__ rowptr, const int* __restrict__ counts,
                          const float* __restrict__ nrm2, const int2* __restrict__ edata,
                          float* __restrict__ w2csr, float* __restrict__ dinv2, int N) {
    int r = (blockIdx.x * blockDim.x + threadIdx.x) >> 6;
    int lane = threadIdx.x & 63;
    if (r >= N) return;
    int cnt = counts[r];
    int start = rowptr[r] - cnt;
    float deg = 0.f;
    if (cnt > 0) {
        uint2 hr = ((const uint2*)(hh + (size_t)r * (NHID / 2)))[lane];
        float nr = nrm2[r];
        for (int k = 0; k < cnt; ++k) {
            int c = edata[start + k].x;
            uint2 hc = ((const uint2*)(hh + (size_t)c * (NHID / 2)))[lane];
            float s = dot2acc(hr.y, hc.y, dot2acc(hr.x, hc.x, 0.f));
            s = waveSum(s);
            float inv = 1.0f / (nr * nrm2[c]);
            float sims = s * inv;
            if (__builtin_expect(fabsf(sims - THRESH) < GUARD, 0)) {
                // rare: recompute h[r], h[c] exactly (f32) from xagg @ W1 + b1
                int j0 = lane * 4;                  // 64 lanes x 4 cols = 256
                float aR[4], aC[4];
#pragma unroll
                for (int q = 0; q < 4; ++q) { aR[q] = b1f[j0 + q]; aC[q] = b1f[j0 + q]; }
                const float* xr = xagg + (size_t)r * NFEAT;
                const float* xc = xagg + (size_t)c * NFEAT;
                for (int kk = 0; kk < NFEAT; ++kk) {
                    float vr = xr[kk], vc = xc[kk];   // wave-broadcast loads
                    float4 wv = *((const float4*)(W1f + (size_t)kk * NHID + j0));
                    aR[0] += vr * wv.x; aC[0] += vc * wv.x;
                    aR[1] += vr * wv.y; aC[1] += vc * wv.y;
                    aR[2] += vr * wv.z; aC[2] += vc * wv.z;
                    aR[3] += vr * wv.w; aC[3] += vc * wv.w;
                }
                float dp = 0.f;
#pragma unroll
                for (int q = 0; q < 4; ++q)
                    dp += fmaxf(aR[q], 0.f) * fmaxf(aC[q], 0.f);
                float s2 = waveSum(dp);
                sims = s2 * inv;
            }
            float w2 = (sims >= THRESH) ? sims : 0.f;
            if (lane == 0) w2csr[start + k] = w2;
            deg += w2;
        }
    }
    if (lane == 0) dinv2[r] = 1.0f / sqrtf(1.0f + deg);
}

// ---- gemm2: g = h @ W2; 32 nodes/block; stages fp16 h tile from hh ----
__global__ __launch_bounds__(256) void k_gemm2(const __half2* __restrict__ hh,
                                               const float* __restrict__ W2f,
                                               float* __restrict__ g, int N) {
    __shared__ __half2 hs[32][NHID / 2 + 1];   // [32][129]
    __shared__ float w2s[NHID * NCLASS];       // 40 KB
    int tid = threadIdx.x;
    int i0 = blockIdx.x * 32;
    for (int idx = tid; idx < NHID * NCLASS; idx += 256) w2s[idx] = W2f[idx];
#pragma unroll
    for (int c = 0; c < 8; ++c) {
        int p = c * 256 + tid;
        int n = p >> 6, kp2 = (p & 63) * 2;
        int i = i0 + n;
        h2x2 v = { __floats2half2_rn(0.f, 0.f), __floats2half2_rn(0.f, 0.f) };
        if (i < N) v = ((const h2x2*)(hh + (size_t)i * (NHID / 2)))[p & 63];
        hs[n][kp2] = v.a;
        hs[n][kp2 + 1] = v.b;
    }
    __syncthreads();
    int wv = tid >> 6;
    int lane = tid & 63;
    int n = lane & 31, half = lane >> 5;
    int j0 = wv * 10 + half * 5;
    int i = i0 + n;
    float acc[5] = {0.f, 0.f, 0.f, 0.f, 0.f};
    for (int kp = 0; kp < NHID / 2; ++kp) {
        float2 hf = __half22float2(hs[n][kp]);
        const float* wrow0 = w2s + (2 * kp) * NCLASS + j0;
        const float* wrow1 = w2s + (2 * kp + 1) * NCLASS + j0;
#pragma unroll
        for (int q = 0; q < 5; ++q)
            acc[q] += hf.x * wrow0[q] + hf.y * wrow1[q];
    }
    if (i < N) {
        float* gp = g + (size_t)i * NCLASS + j0;
#pragma unroll
        for (int q = 0; q < 5; ++q) gp[q] = acc[q];
    }
}

// ---- gather2: out[r] = dinv2^2*g[r] + b2 + sum_e dinv2[r]*w2*dinv2[c]*g[c] ----
__global__ void k_gather2(const float* __restrict__ g, const int* __restrict__ rowptr,
                          const int* __restrict__ counts, const float* __restrict__ dinv2,
                          const float* __restrict__ b2f, const int2* __restrict__ edata,
                          const float* __restrict__ w2csr, float* __restrict__ out, int N) {
    int r = (blockIdx.x * blockDim.x + threadIdx.x) >> 6;
    int lane = threadIdx.x & 63;
    if (r >= N || lane >= NCLASS) return;
    int cnt = counts[r];
    int start = rowptr[r] - cnt;
    float dr = dinv2[r];
    float acc = dr * dr * g[(size_t)r * NCLASS + lane] + b2f[lane];
    for (int k = 0; k < cnt; ++k) {
        int c = edata[start + k].x;
        float w2 = w2csr[start + k];
        acc += dr * w2 * dinv2[c] * g[(size_t)c * NCLASS + lane];
    }
    out[(size_t)r * NCLASS + lane] = acc;
}

extern "C" void kernel_launch(void* const* d_in, const int* in_sizes, int n_in,
                              void* d_out, int out_size, void* d_ws, size_t ws_size,
                              hipStream_t stream) {
    const float* x  = (const float*)d_in[0];
    const int* row  = (const int*)d_in[1];
    const int* col  = (const int*)d_in[2];
    const float* W1 = (const float*)d_in[3];
    const float* b1 = (const float*)d_in[4];
    const float* W2 = (const float*)d_in[5];
    const float* b2 = (const float*)d_in[6];
    float* out = (float*)d_out;
    const int N = in_sizes[0] / NFEAT;
    const int E = in_sizes[1];

    // ---- workspace layout (~120 MB peak; f32 h eliminated) ----
    char* ws = (char*)d_ws;
    size_t off = 0;
    auto alloc = [&](size_t bytes) {
        char* p = ws + off;
        off += (bytes + 255) & ~(size_t)255;
        return p;
    };
    float*   xagg   = (float*)alloc((size_t)N * NFEAT * 4);   // live thru att2csr; g reuses
    __half2* hh     = (__half2*)alloc((size_t)N * NHID * 2);  // fp16 h mirror
    __half2* xn     = hh;                                     // normalized fp16 x overlay
    float*   w1buf  = (float*)alloc((size_t)E * 4);
    float*   w2csr  = (float*)alloc((size_t)E * 4);
    int2*    edata  = (int2*)alloc((size_t)E * 8);
    float*   nrm    = (float*)alloc((size_t)N * 4);           // nrm1, then nrm2
    float*   deg    = (float*)alloc((size_t)N * 4);           // degsum layer 1
    float*   dinv2  = (float*)alloc((size_t)N * 4);
    int*     counts = (int*)alloc((size_t)N * 4);
    int*     rowptr = (int*)alloc((size_t)N * 4);
    int*     bsum   = (int*)alloc(512 * 4);
    float*   g      = xagg;                                   // overwritten at gemm2

    const int e4Blocks = (E + 15) / 16;   // 4 edges/wave, 4 waves/block
    const int eBlocks1 = (E + 255) / 256;
    const int nBlocks4 = (N + 3) / 4;
    const int scanB    = (N + 255) / 256;

    // ---- layer 1 ----
    k_prep<<<nBlocks4, 256, 0, stream>>>(x, xn, nrm, deg, counts, N);
    k_att1<<<e4Blocks, 256, 0, stream>>>(x, xn, row, col, nrm, w1buf, deg, counts, E);
    k_scan1<<<scanB, 256, 0, stream>>>(counts, rowptr, bsum, N);
    k_scan2<<<1, 512, 0, stream>>>(bsum, scanB);
    k_scan3<<<scanB, 256, 0, stream>>>(rowptr, bsum, N);
    k_fill<<<eBlocks1, 256, 0, stream>>>(row, col, w1buf, deg, rowptr, edata, E);
    k_gather1<<<nBlocks4, 256, 0, stream>>>(x, rowptr, counts, deg, edata, xagg, N);
    k_gemm1h<<<(N + 63) / 64, 256, 0, stream>>>(xagg, W1, b1, hh, nrm, N);

    // ---- layer 2 (reuses layer-1 CSR; fp16 h gathers; guard recomputes from xagg) ----
    k_att2csr<<<nBlocks4, 256, 0, stream>>>(xagg, W1, b1, hh, rowptr, counts, nrm,
                                            edata, w2csr, dinv2, N);
    k_gemm2<<<(N + 31) / 32, 256, 0, stream>>>(hh, W2, g, N);
    k_gather2<<<nBlocks4, 256, 0, stream>>>(g, rowptr, counts, dinv2, b2, edata, w2csr,
                                            out, N);
}

// Round 12
// 464.545 us; speedup vs baseline: 1.0521x; 1.0521x over previous
//
#include <hip/hip_runtime.h>
#include <hip/hip_bf16.h>
#include <hip/hip_fp16.h>

#define NFEAT 128
#define NHID  256
#define NCLASS 40
#define THRESH 0.1f
#define FEPS   1e-8f
#define GUARD  1e-3f
#define GUARD2 4e-3f

struct h2x2 { __half2 a, b; };   // 8-byte packed 4x fp16

typedef _Float16 v2h __attribute__((ext_vector_type(2)));
typedef _Float16 v8h __attribute__((ext_vector_type(8)));
typedef float f32x4 __attribute__((ext_vector_type(4)));

// fdot2: s += dot(2xfp16, 2xfp16) in one VALU op where available
__device__ __forceinline__ float dot2acc(unsigned int a, unsigned int b, float s) {
#if __has_builtin(__builtin_amdgcn_fdot2)
    return __builtin_amdgcn_fdot2(__builtin_bit_cast(v2h, a),
                                  __builtin_bit_cast(v2h, b), s, false);
#else
    float2 fa = __half22float2(__builtin_bit_cast(__half2, a));
    float2 fb = __half22float2(__builtin_bit_cast(__half2, b));
    return s + fa.x * fb.x + fa.y * fb.y;
#endif
}

__device__ __forceinline__ float waveSum(float v) {
#pragma unroll
    for (int off = 32; off > 0; off >>= 1) v += __shfl_xor(v, off, 64);
    return v;
}

__device__ __forceinline__ float qSum16(float v) {
#pragma unroll
    for (int off = 8; off > 0; off >>= 1) v += __shfl_xor(v, off, 64);
    return v;
}

// ---- prep: nrm + normalized fp16 xn + zero-init deg/counts (wave per node) ----
__global__ void k_prep(const float* __restrict__ x, __half2* __restrict__ xn,
                       float* __restrict__ nrm, float* __restrict__ deg,
                       int* __restrict__ counts, int N) {
    int r = (blockIdx.x * blockDim.x + threadIdx.x) >> 6;
    int lane = threadIdx.x & 63;
    if (r >= N) return;
    float2 a = ((const float2*)(x + (size_t)r * NFEAT))[lane];
    float s = waveSum(a.x * a.x + a.y * a.y);
    float nr = fmaxf(sqrtf(s), FEPS);
    float inv = 1.0f / nr;
    xn[(size_t)r * (NFEAT / 2) + lane] = __floats2half2_rn(a.x * inv, a.y * inv);
    if (lane == 0) {
        nrm[r] = nr;
        deg[r] = 0.0f;
        counts[r] = 0;
    }
}

// ---- build W1 in MFMA B-fragment order: w1x[((kb*16+ct)*64+lane)] = 8 fp16,
//      element j = W1[kb*32 + (lane>>4)*8 + j][ct*16 + (lane&15)] ----
__global__ void k_w1frag(const float* __restrict__ W1f, v8h* __restrict__ w1x) {
    int id = blockIdx.x * 256 + threadIdx.x;   // 0..4095
    int frag = id >> 6, lane = id & 63;
    int kb = frag >> 4, ct = frag & 15;
    int kbase = kb * 32 + (lane >> 4) * 8;
    int n = ct * 16 + (lane & 15);
    v8h v;
#pragma unroll
    for (int j = 0; j < 8; ++j)
        v[j] = (_Float16)W1f[(size_t)(kbase + j) * NHID + n];
    w1x[id] = v;
}

// ---- att1: 4 edges/wave (16-lane groups) over normalized fp16 x; fdot2 ----
__global__ void k_att1(const float* __restrict__ xf, const __half2* __restrict__ xn,
                       const int* __restrict__ row, const int* __restrict__ col,
                       const float* __restrict__ nrm,
                       float* __restrict__ w1, float* __restrict__ deg,
                       int* __restrict__ counts, int E) {
    int wid = (blockIdx.x * blockDim.x + threadIdx.x) >> 6;
    int lane = threadIdx.x & 63;
    int g = lane >> 4, l16 = lane & 15;
    int e = wid * 4 + g;
    if (e >= E) return;
    int r = row[e], c = col[e];
    uint4 av = ((const uint4*)(xn + (size_t)r * (NFEAT / 2)))[l16];
    uint4 bv = ((const uint4*)(xn + (size_t)c * (NFEAT / 2)))[l16];
    float s = 0.f;
    s = dot2acc(av.x, bv.x, s);
    s = dot2acc(av.y, bv.y, s);
    s = dot2acc(av.z, bv.z, s);
    s = dot2acc(av.w, bv.w, s);
    float sims = qSum16(s);
    if (__builtin_expect(fabsf(sims - THRESH) < GUARD, 0)) {
        const float4* fr = (const float4*)(xf + (size_t)r * NFEAT);
        const float4* fc = (const float4*)(xf + (size_t)c * NFEAT);
        float4 a0 = fr[l16], a1 = fr[l16 + 16];
        float4 b0 = fc[l16], b1 = fc[l16 + 16];
        float s2 = qSum16(a0.x * b0.x + a0.y * b0.y + a0.z * b0.z + a0.w * b0.w +
                          a1.x * b1.x + a1.y * b1.y + a1.z * b1.z + a1.w * b1.w);
        sims = s2 / (nrm[r] * nrm[c]);
    }
    if (l16 == 0) {
        float w = (sims >= THRESH && r != c) ? sims : 0.0f;
        w1[e] = w;
        if (w != 0.0f) {
            unsafeAtomicAdd(&deg[r], w);
            atomicAdd(&counts[r], 1);
        }
    }
}

// ---- exclusive scan of counts -> rowptr (3-kernel, N <= 512*256) ----
__global__ __launch_bounds__(256) void k_scan1(const int* __restrict__ counts,
                                               int* __restrict__ rowptr,
                                               int* __restrict__ bsum, int N) {
    __shared__ int tmp[256];
    int t = threadIdx.x, i = blockIdx.x * 256 + t;
    int v = (i < N) ? counts[i] : 0;
    tmp[t] = v;
    __syncthreads();
    for (int off = 1; off < 256; off <<= 1) {
        int add = (t >= off) ? tmp[t - off] : 0;
        __syncthreads();
        tmp[t] += add;
        __syncthreads();
    }
    if (i < N) rowptr[i] = tmp[t] - v;
    if (t == 255) bsum[blockIdx.x] = tmp[t];
}

__global__ __launch_bounds__(512) void k_scan2(int* __restrict__ bsum, int nb) {
    __shared__ int tmp[512];
    int t = threadIdx.x;
    int v = (t < nb) ? bsum[t] : 0;
    tmp[t] = v;
    __syncthreads();
    for (int off = 1; off < 512; off <<= 1) {
        int add = (t >= off) ? tmp[t - off] : 0;
        __syncthreads();
        tmp[t] += add;
        __syncthreads();
    }
    if (t < nb) bsum[t] = tmp[t] - v;
}

__global__ void k_scan3(int* __restrict__ rowptr, const int* __restrict__ bsum, int N) {
    int i = blockIdx.x * 256 + threadIdx.x;
    if (i < N) rowptr[i] += bsum[blockIdx.x];
}

// ---- fill CSR: edata[pos] = (col, norm); dinv computed inline from deg ----
__global__ void k_fill(const int* __restrict__ row, const int* __restrict__ col,
                       const float* __restrict__ wbuf, const float* __restrict__ deg,
                       int* __restrict__ rowptr, int2* __restrict__ edata, int E) {
    int e = blockIdx.x * blockDim.x + threadIdx.x;
    if (e >= E) return;
    float w = wbuf[e];
    if (w == 0.0f) return;
    int r = row[e], c = col[e];
    float dr = 1.0f / sqrtf(1.0f + deg[r]);
    float dc = 1.0f / sqrtf(1.0f + deg[c]);
    float nm = dr * w * dc;
    int pos = atomicAdd(&rowptr[r], 1);
    edata[pos] = make_int2(c, __float_as_int(nm));
}

// ---- gather1: xagg[r] = dinv^2*x[r] + sum_e nm*x[c]  (wave per node, f32) ----
__global__ void k_gather1(const float* __restrict__ xf, const int* __restrict__ rowptr,
                          const int* __restrict__ counts, const float* __restrict__ deg,
                          const int2* __restrict__ edata, float* __restrict__ xagg, int N) {
    int r = (blockIdx.x * blockDim.x + threadIdx.x) >> 6;
    int lane = threadIdx.x & 63;
    if (r >= N) return;
    int cnt = counts[r];
    int start = rowptr[r] - cnt;
    float d = 1.0f / sqrtf(1.0f + deg[r]);
    float2 xa = ((const float2*)(xf + (size_t)r * NFEAT))[lane];
    float2 acc = make_float2(d * d * xa.x, d * d * xa.y);
    for (int k = 0; k < cnt; ++k) {
        int2 ed = edata[start + k];
        float nm = __int_as_float(ed.y);
        float2 xv = ((const float2*)(xf + (size_t)ed.x * NFEAT))[lane];
        acc.x += nm * xv.x;
        acc.y += nm * xv.y;
    }
    ((float2*)(xagg + (size_t)r * NFEAT))[lane] = acc;
}

// ---- gemm1h v7 (MFMA): h = relu(xagg @ W1 + b1); 64 nodes/block, wave=16 nodes.
//      A: fp16 xagg tile in LDS; B: pre-swizzled W1 frags from L2.
//      Emits fp16 hh (2B stores) + fused nrm2. No f32 h. ----
__global__ __launch_bounds__(256) void k_gemm1h(const float* __restrict__ xagg,
                                                const v8h* __restrict__ w1x,
                                                const float* __restrict__ b1f,
                                                __half* __restrict__ hh16,
                                                float* __restrict__ nrm2, int N) {
    __shared__ __half2 xsh[64][68];   // [64 nodes][64 half2 + 4 pad] = 17.4 KB
    int tid = threadIdx.x;
    int i0 = blockIdx.x * 64;

    // stage xagg tile as fp16 (coalesced float2 reads, conflict-free LDS writes)
#pragma unroll
    for (int it = 0; it < 16; ++it) {
        int idx = it * 256 + tid;          // 4096 half2
        int n = idx >> 6, kq = idx & 63;
        int i = i0 + n;
        float2 v = make_float2(0.f, 0.f);
        if (i < N) v = ((const float2*)(xagg + (size_t)i * NFEAT))[kq];
        xsh[n][kq] = __floats2half2_rn(v.x, v.y);
    }
    __syncthreads();

    int w = tid >> 6, lane = tid & 63;
    int c = lane & 15, q = lane >> 4;
    int nb = w * 16;                       // wave's node base within tile

    f32x4 acc[16];
#pragma unroll
    for (int t = 0; t < 16; ++t) acc[t] = (f32x4){0.f, 0.f, 0.f, 0.f};

#pragma unroll
    for (int kb = 0; kb < 4; ++kb) {
        // A-frag: row m=c, k = kb*32 + q*8 + j  ->  half2 col kb*16 + q*4
        v8h a = *((const v8h*)&xsh[nb + c][kb * 16 + q * 4]);
        const v8h* bp = w1x + (size_t)(kb * 16) * 64 + lane;
#pragma unroll
        for (int ct = 0; ct < 16; ++ct) {
            v8h b = bp[ct * 64];
            acc[ct] = __builtin_amdgcn_mfma_f32_16x16x32_f16(a, b, acc[ct], 0, 0, 0);
        }
    }

    // epilogue: bias + ReLU, fp16 stores, fused row-norm accumulation
    float s2[4] = {0.f, 0.f, 0.f, 0.f};
    bool full = (i0 + 64 <= N);
#pragma unroll
    for (int ct = 0; ct < 16; ++ct) {
        int n = ct * 16 + c;
        float bias = b1f[n];
        f32x4 d = acc[ct];
#pragma unroll
        for (int reg = 0; reg < 4; ++reg) {
            int node = i0 + nb + q * 4 + reg;   // D row = q*4+reg
            float v = fmaxf(d[reg] + bias, 0.f);
            s2[reg] += v * v;
            if (full || node < N) hh16[(size_t)node * NHID + n] = __float2half(v);
        }
    }
#pragma unroll
    for (int off = 1; off < 16; off <<= 1) {
#pragma unroll
        for (int reg = 0; reg < 4; ++reg) s2[reg] += __shfl_xor(s2[reg], off, 64);
    }
    if (c == 0) {
        int base = i0 + nb + q * 4;
#pragma unroll
        for (int reg = 0; reg < 4; ++reg)
            if (base + reg < N) nrm2[base + reg] = fmaxf(sqrtf(s2[reg]), FEPS);
    }
}

// ---- att2 over CSR from fp16 h (fdot2); guard recomputes h rows from xagg@W1 ----
__global__ void k_att2csr(const float* __restrict__ xagg, const float* __restrict__ W1f,
                          const float* __restrict__ b1f, const __half2* __restrict__ hh,
                          const int* __restrict__ rowptr, const int* __restrict__ counts,
                          const float* __restrict__ nrm2, const int2* __restrict__ edata,
                          float* __restrict__ w2csr, float* __restrict__ dinv2, int N) {
    int r = (blockIdx.x * blockDim.x + threadIdx.x) >> 6;
    int lane = threadIdx.x & 63;
    if (r >= N) return;
    int cnt = counts[r];
    int start = rowptr[r] - cnt;
    float deg = 0.f;
    if (cnt > 0) {
        uint2 hr = ((const uint2*)(hh + (size_t)r * (NHID / 2)))[lane];
        float nr = nrm2[r];
        for (int k = 0; k < cnt; ++k) {
            int c = edata[start + k].x;
            uint2 hc = ((const uint2*)(hh + (size_t)c * (NHID / 2)))[lane];
            float s = dot2acc(hr.y, hc.y, dot2acc(hr.x, hc.x, 0.f));
            s = waveSum(s);
            float inv = 1.0f / (nr * nrm2[c]);
            float sims = s * inv;
            if (__builtin_expect(fabsf(sims - THRESH) < GUARD2, 0)) {
                // rare: recompute h[r], h[c] exactly (f32) from xagg @ W1 + b1
                int j0 = lane * 4;                  // 64 lanes x 4 cols = 256
                float aR[4], aC[4];
#pragma unroll
                for (int q = 0; q < 4; ++q) { aR[q] = b1f[j0 + q]; aC[q] = b1f[j0 + q]; }
                const float* xr = xagg + (size_t)r * NFEAT;
                const float* xc = xagg + (size_t)c * NFEAT;
                for (int kk = 0; kk < NFEAT; ++kk) {
                    float vr = xr[kk], vc = xc[kk];   // wave-broadcast loads
                    float4 wv = *((const float4*)(W1f + (size_t)kk * NHID + j0));
                    aR[0] += vr * wv.x; aC[0] += vc * wv.x;
                    aR[1] += vr * wv.y; aC[1] += vc * wv.y;
                    aR[2] += vr * wv.z; aC[2] += vc * wv.z;
                    aR[3] += vr * wv.w; aC[3] += vc * wv.w;
                }
                float dp = 0.f;
#pragma unroll
                for (int q = 0; q < 4; ++q)
                    dp += fmaxf(aR[q], 0.f) * fmaxf(aC[q], 0.f);
                float s2 = waveSum(dp);
                // exact norms too (nrm2 from MFMA h is inexact at ~1e-3 level,
                // but sims scales ~identically; sign of (sims-TH) is what matters
                // and s2/(nr*nrm2[c]) matches reference to ~1e-3*TH — accept)
                sims = s2 * inv;
            }
            float w2 = (sims >= THRESH) ? sims : 0.f;
            if (lane == 0) w2csr[start + k] = w2;
            deg += w2;
        }
    }
    if (lane == 0) dinv2[r] = 1.0f / sqrtf(1.0f + deg);
}

// ---- gemm2: g = h @ W2; 32 nodes/block; stages fp16 h tile from hh ----
__global__ __launch_bounds__(256) void k_gemm2(const __half2* __restrict__ hh,
                                               const float* __restrict__ W2f,
                                               float* __restrict__ g, int N) {
    __shared__ __half2 hs[32][NHID / 2 + 1];   // [32][129]
    __shared__ float w2s[NHID * NCLASS];       // 40 KB
    int tid = threadIdx.x;
    int i0 = blockIdx.x * 32;
    for (int idx = tid; idx < NHID * NCLASS; idx += 256) w2s[idx] = W2f[idx];
#pragma unroll
    for (int c = 0; c < 8; ++c) {
        int p = c * 256 + tid;
        int n = p >> 6, kp2 = (p & 63) * 2;
        int i = i0 + n;
        h2x2 v = { __floats2half2_rn(0.f, 0.f), __floats2half2_rn(0.f, 0.f) };
        if (i < N) v = ((const h2x2*)(hh + (size_t)i * (NHID / 2)))[p & 63];
        hs[n][kp2] = v.a;
        hs[n][kp2 + 1] = v.b;
    }
    __syncthreads();
    int wv = tid >> 6;
    int lane = tid & 63;
    int n = lane & 31, half = lane >> 5;
    int j0 = wv * 10 + half * 5;
    int i = i0 + n;
    float acc[5] = {0.f, 0.f, 0.f, 0.f, 0.f};
    for (int kp = 0; kp < NHID / 2; ++kp) {
        float2 hf = __half22float2(hs[n][kp]);
        const float* wrow0 = w2s + (2 * kp) * NCLASS + j0;
        const float* wrow1 = w2s + (2 * kp + 1) * NCLASS + j0;
#pragma unroll
        for (int q = 0; q < 5; ++q)
            acc[q] += hf.x * wrow0[q] + hf.y * wrow1[q];
    }
    if (i < N) {
        float* gp = g + (size_t)i * NCLASS + j0;
#pragma unroll
        for (int q = 0; q < 5; ++q) gp[q] = acc[q];
    }
}

// ---- gather2: out[r] = dinv2^2*g[r] + b2 + sum_e dinv2[r]*w2*dinv2[c]*g[c] ----
__global__ void k_gather2(const float* __restrict__ g, const int* __restrict__ rowptr,
                          const int* __restrict__ counts, const float* __restrict__ dinv2,
                          const float* __restrict__ b2f, const int2* __restrict__ edata,
                          const float* __restrict__ w2csr, float* __restrict__ out, int N) {
    int r = (blockIdx.x * blockDim.x + threadIdx.x) >> 6;
    int lane = threadIdx.x & 63;
    if (r >= N || lane >= NCLASS) return;
    int cnt = counts[r];
    int start = rowptr[r] - cnt;
    float dr = dinv2[r];
    float acc = dr * dr * g[(size_t)r * NCLASS + lane] + b2f[lane];
    for (int k = 0; k < cnt; ++k) {
        int c = edata[start + k].x;
        float w2 = w2csr[start + k];
        acc += dr * w2 * dinv2[c] * g[(size_t)c * NCLASS + lane];
    }
    out[(size_t)r * NCLASS + lane] = acc;
}

extern "C" void kernel_launch(void* const* d_in, const int* in_sizes, int n_in,
                              void* d_out, int out_size, void* d_ws, size_t ws_size,
                              hipStream_t stream) {
    const float* x  = (const float*)d_in[0];
    const int* row  = (const int*)d_in[1];
    const int* col  = (const int*)d_in[2];
    const float* W1 = (const float*)d_in[3];
    const float* b1 = (const float*)d_in[4];
    const float* W2 = (const float*)d_in[5];
    const float* b2 = (const float*)d_in[6];
    float* out = (float*)d_out;
    const int N = in_sizes[0] / NFEAT;
    const int E = in_sizes[1];

    // ---- workspace layout (~120 MB peak) ----
    char* ws = (char*)d_ws;
    size_t off = 0;
    auto alloc = [&](size_t bytes) {
        char* p = ws + off;
        off += (bytes + 255) & ~(size_t)255;
        return p;
    };
    float*   xagg   = (float*)alloc((size_t)N * NFEAT * 4);   // live thru att2csr; g reuses
    __half2* hh     = (__half2*)alloc((size_t)N * NHID * 2);  // fp16 h mirror
    __half2* xn     = hh;                                     // normalized fp16 x overlay
    float*   w1buf  = (float*)alloc((size_t)E * 4);
    float*   w2csr  = (float*)alloc((size_t)E * 4);
    int2*    edata  = (int2*)alloc((size_t)E * 8);
    float*   nrm    = (float*)alloc((size_t)N * 4);           // nrm1, then nrm2
    float*   deg    = (float*)alloc((size_t)N * 4);           // degsum layer 1
    float*   dinv2  = (float*)alloc((size_t)N * 4);
    int*     counts = (int*)alloc((size_t)N * 4);
    int*     rowptr = (int*)alloc((size_t)N * 4);
    int*     bsum   = (int*)alloc(512 * 4);
    v8h*     w1x    = (v8h*)alloc(4096 * 16);                 // W1 B-fragments (64 KB)
    float*   g      = xagg;                                   // overwritten at gemm2

    const int e4Blocks = (E + 15) / 16;   // 4 edges/wave, 4 waves/block
    const int eBlocks1 = (E + 255) / 256;
    const int nBlocks4 = (N + 3) / 4;
    const int scanB    = (N + 255) / 256;

    // ---- layer 1 ----
    k_prep<<<nBlocks4, 256, 0, stream>>>(x, xn, nrm, deg, counts, N);
    k_w1frag<<<16, 256, 0, stream>>>(W1, w1x);
    k_att1<<<e4Blocks, 256, 0, stream>>>(x, xn, row, col, nrm, w1buf, deg, counts, E);
    k_scan1<<<scanB, 256, 0, stream>>>(counts, rowptr, bsum, N);
    k_scan2<<<1, 512, 0, stream>>>(bsum, scanB);
    k_scan3<<<scanB, 256, 0, stream>>>(rowptr, bsum, N);
    k_fill<<<eBlocks1, 256, 0, stream>>>(row, col, w1buf, deg, rowptr, edata, E);
    k_gather1<<<nBlocks4, 256, 0, stream>>>(x, rowptr, counts, deg, edata, xagg, N);
    k_gemm1h<<<(N + 63) / 64, 256, 0, stream>>>(xagg, w1x, b1, (__half*)hh, nrm, N);

    // ---- layer 2 (reuses layer-1 CSR; fp16 h gathers; guard recomputes from xagg) ----
    k_att2csr<<<nBlocks4, 256, 0, stream>>>(xagg, W1, b1, hh, rowptr, counts, nrm,
                                            edata, w2csr, dinv2, N);
    k_gemm2<<<(N + 31) / 32, 256, 0, stream>>>(hh, W2, g, N);
    k_gather2<<<nBlocks4, 256, 0, stream>>>(g, rowptr, counts, dinv2, b2, edata, w2csr,
                                            out, N);
}